// Round 2
// baseline (366.731 us; speedup 1.0000x reference)
//
#include <hip/hip_runtime.h>
#include <cstdint>

// out[s,b,m,n] = sum_k (x+66)*0.03 * (y-160)*0.025
// With y' = y-128 (both x, y' fit int8):
//   out = 7.5e-4 * ( S' - 32*Rx[m] + 66*Cy[n] - 10813440 ),  S' = sum x*y'  (int32-exact via i8 MFMA)
// Rx = row sums of x (computed during fused fp32->i8 A-staging), Cy = col sums of y (prepass).

#define NG 56  // 7*8 gemms, each 1024^3

typedef int v4i  __attribute__((ext_vector_type(4)));
typedef int v16i __attribute__((ext_vector_type(16)));

#define GLOAD16(g, l) __builtin_amdgcn_global_load_lds( \
    (const __attribute__((address_space(1))) void*)(g), \
    (__attribute__((address_space(3))) void*)(l), 16, 0, 0)

// fp32 (integer-valued, [-128,127]) -> i8 byte, exact: exponent-pin + bias-flip
__device__ __forceinline__ unsigned pack4(float4 v, float& s) {
    s += (v.x + v.y) + (v.z + v.w);
    unsigned b0 = __float_as_uint(v.x + 8388736.0f);  // 2^23 + 128
    unsigned b1 = __float_as_uint(v.y + 8388736.0f);
    unsigned b2 = __float_as_uint(v.z + 8388736.0f);
    unsigned b3 = __float_as_uint(v.w + 8388736.0f);
    return ((b0 & 0xFFu) | ((b1 & 0xFFu) << 8) | ((b2 & 0xFFu) << 16) | ((b3 & 0xFFu) << 24))
           ^ 0x80808080u;
}

// ---- prepass: y fp32 [b][k][n] -> yt i8 [b][n][k] (= y-128), + col sums Cy ----
__global__ __launch_bounds__(256) void k_prep_y(const float* __restrict__ y,
                                                unsigned char* __restrict__ yt,
                                                float* __restrict__ cy) {
    __shared__ float tile[64][65];
    __shared__ float csum[4][64];
    int b  = blockIdx.x >> 8;
    int t  = blockIdx.x & 255;
    int kt = (t >> 4) * 64, nt = (t & 15) * 64;
    int tx = threadIdx.x & 63;
    int ty = threadIdx.x >> 6;
    const float* src = y + ((size_t)b << 20) + (size_t)kt * 1024 + nt;
    float part = 0.f;
#pragma unroll
    for (int r = 0; r < 16; ++r) {
        int kk = r * 4 + ty;
        float v = src[(size_t)kk * 1024 + tx];
        tile[kk][tx] = v;
        part += v;
    }
    csum[ty][tx] = part;
    __syncthreads();
    if (threadIdx.x < 64) {
        float s = csum[0][tx] + csum[1][tx] + csum[2][tx] + csum[3][tx];
        atomicAdd(&cy[b * 1024 + nt + tx], s);   // exact: integer sums < 2^24
    }
    int ky = threadIdx.x & 15;   // k-quad within tile
    int ny = threadIdx.x >> 4;   // 0..15
#pragma unroll
    for (int r = 0; r < 4; ++r) {
        int nn = r * 16 + ny;
        // y in [0,255]: pin exponent with +2^23, low byte = y, ^0x80 gives (y-128) as i8
        unsigned b0 = __float_as_uint(tile[ky * 4 + 0][nn] + 8388608.0f);
        unsigned b1 = __float_as_uint(tile[ky * 4 + 1][nn] + 8388608.0f);
        unsigned b2 = __float_as_uint(tile[ky * 4 + 2][nn] + 8388608.0f);
        unsigned b3 = __float_as_uint(tile[ky * 4 + 3][nn] + 8388608.0f);
        unsigned p = ((b0 & 0xFFu) | ((b1 & 0xFFu) << 8) | ((b2 & 0xFFu) << 16) |
                      ((b3 & 0xFFu) << 24)) ^ 0x80808080u;
        *(unsigned*)&yt[((size_t)b << 20) + (size_t)(nt + nn) * 1024 + kt + ky * 4] = p;
    }
}

// ---- fused GEMM: 128x128 tile, 4 waves, BK=64, i8 MFMA, A reg-staged from fp32 ----
__global__ __launch_bounds__(256) void k_gemm(const float* __restrict__ x,
                                              const unsigned char* __restrict__ yt,
                                              const float* __restrict__ cy,
                                              float* __restrict__ out) {
    __shared__ __align__(16) unsigned char As[2][128 * 64];
    __shared__ __align__(16) unsigned char Bs[2][128 * 64];
    __shared__ float rxs[128];

    // bijective XCD swizzle (3584 % 8 == 0); consecutive t share A-panel -> L2 reuse
    int bid = blockIdx.x;
    int wg  = (bid & 7) * (NG * 64 / 8) + (bid >> 3);
    int g   = wg >> 6;
    int t   = wg & 63;
    int m0  = (t >> 3) * 128, n0 = (t & 7) * 128;
    int b   = g & 7;

    int tid = threadIdx.x, lane = tid & 63, w = tid >> 6;
    int wm = w >> 1, wn = w & 1;

    // A staging: thread owns row (tid>>1), k-half (tid&1)*32 of each 64-wide K-step
    const float* ax = x + (size_t)g * 1048576 + (size_t)(m0 + (tid >> 1)) * 1024 + (tid & 1) * 32;
    const unsigned char* by = yt + ((size_t)b << 20) + (size_t)n0 * 1024;

    v16i acc[2][2];
#pragma unroll
    for (int i = 0; i < 2; ++i)
#pragma unroll
        for (int j = 0; j < 2; ++j)
#pragma unroll
            for (int q = 0; q < 16; ++q) acc[i][j][q] = 0;

    float rs = 0.f;
    float4 L[8];

    // prologue: stage kt=0 into buffer 0
#pragma unroll
    for (int j = 0; j < 8; ++j) L[j] = *(const float4*)(ax + j * 4);
#pragma unroll
    for (int r = 0; r < 2; ++r) {
        int c = r * 256 + tid;
        GLOAD16(by + (size_t)(c >> 2) * 1024 + (c & 3) * 16,
                &Bs[0][(r * 256 + (tid & ~63)) * 16]);
    }
    {
        uint4 w0, w1;
        w0.x = pack4(make_float4(L[0].x, L[0].y, L[0].z, L[0].w), rs);
        w0.y = pack4(L[1], rs); w0.z = pack4(L[2], rs); w0.w = pack4(L[3], rs);
        w1.x = pack4(L[4], rs); w1.y = pack4(L[5], rs);
        w1.z = pack4(L[6], rs); w1.w = pack4(L[7], rs);
        *(uint4*)&As[0][tid * 32] = w0;
        *(uint4*)&As[0][tid * 32 + 16] = w1;
    }
    __syncthreads();

    int cur = 0;
    for (int kt = 0; kt < 16; ++kt) {
        bool pf = kt < 15;
        if (pf) {
#pragma unroll
            for (int j = 0; j < 8; ++j)
                L[j] = *(const float4*)(ax + (kt + 1) * 64 + j * 4);
#pragma unroll
            for (int r = 0; r < 2; ++r) {
                int c = r * 256 + tid;
                GLOAD16(by + (size_t)(c >> 2) * 1024 + (kt + 1) * 64 + (c & 3) * 16,
                        &Bs[cur ^ 1][(r * 256 + (tid & ~63)) * 16]);
            }
        }
        // fragments: 32x32x32 i8 — lane holds row=lane&31, k=(lane>>5)*16 + 0..15
        int arow = lane & 31, kg = (lane >> 5) * 16;
        v4i a[2][2], bv[2][2];
#pragma unroll
        for (int fi = 0; fi < 2; ++fi)
#pragma unroll
            for (int kk = 0; kk < 2; ++kk) {
                a[fi][kk]  = *(const v4i*)&As[cur][(wm * 64 + fi * 32 + arow) * 64 + kk * 32 + kg];
                bv[fi][kk] = *(const v4i*)&Bs[cur][(wn * 64 + fi * 32 + arow) * 64 + kk * 32 + kg];
            }
#pragma unroll
        for (int kk = 0; kk < 2; ++kk)
#pragma unroll
            for (int fi = 0; fi < 2; ++fi)
#pragma unroll
                for (int fj = 0; fj < 2; ++fj)
                    acc[fi][fj] = __builtin_amdgcn_mfma_i32_32x32x32_i8(
                        a[fi][kk], bv[fj][kk], acc[fi][fj], 0, 0, 0);
        if (pf) {
            uint4 w0, w1;
            w0.x = pack4(L[0], rs); w0.y = pack4(L[1], rs);
            w0.z = pack4(L[2], rs); w0.w = pack4(L[3], rs);
            w1.x = pack4(L[4], rs); w1.y = pack4(L[5], rs);
            w1.z = pack4(L[6], rs); w1.w = pack4(L[7], rs);
            *(uint4*)&As[cur ^ 1][tid * 32] = w0;
            *(uint4*)&As[cur ^ 1][tid * 32 + 16] = w1;
        }
        __syncthreads();
        cur ^= 1;
    }

    // row sums: thread pair (2r, 2r+1) holds halves of row r
    float st = rs + __shfl_xor(rs, 1);
    if ((tid & 1) == 0) rxs[tid >> 1] = st;
    __syncthreads();

    // epilogue: out = 7.5e-4 * (S' - 32*Rx + 66*Cy - 10813440)
    const float* cyp = cy + b * 1024 + n0 + wn * 64;
    float* og = out + (size_t)g * 1048576 + (size_t)(m0 + wm * 64) * 1024 + n0 + wn * 64;
    int col = lane & 31, r4 = (lane >> 5) * 4;
#pragma unroll
    for (int fi = 0; fi < 2; ++fi)
#pragma unroll
        for (int fj = 0; fj < 2; ++fj) {
            int cc = fj * 32 + col;
            float cv = cyp[cc];
            v16i v = acc[fi][fj];
#pragma unroll
            for (int q = 0; q < 16; ++q) {
                int rl = (q & 3) + 8 * (q >> 2) + r4;   // C/D: col=lane&31, row=(reg&3)+8*(reg>>2)+4*(lane>>5)
                float rxv = rxs[wm * 64 + fi * 32 + rl];
                og[(size_t)(fi * 32 + rl) * 1024 + cc] =
                    7.5e-4f * ((float)v[q] - 32.0f * rxv + 66.0f * cv - 10813440.0f);
            }
        }
}

// ---- emergency fallback: naive tiled fp32 (only if ws is tiny) ----
__global__ void k_naive(const float* __restrict__ x, const float* __restrict__ y,
                        float* __restrict__ out) {
    int g = blockIdx.z, b = g & 7;
    int tx = threadIdx.x, ty = threadIdx.y;
    int m = blockIdx.y * 16 + ty, n = blockIdx.x * 16 + tx;
    __shared__ float a[16][17], bs[16][17];
    float s = 0.f;
    for (int kt = 0; kt < 64; ++kt) {
        a[ty][tx]  = x[(size_t)g * 1048576 + (size_t)m * 1024 + kt * 16 + tx];
        bs[ty][tx] = y[(size_t)b * 1048576 + (size_t)(kt * 16 + ty) * 1024 + n];
        __syncthreads();
#pragma unroll
        for (int j = 0; j < 16; ++j)
            s += ((a[ty][j] + 66.0f) * 0.03f) * ((bs[j][tx] - 160.0f) * 0.025f);
        __syncthreads();
    }
    out[(size_t)g * 1048576 + (size_t)m * 1024 + n] = s;
}

extern "C" void kernel_launch(void* const* d_in, const int* in_sizes, int n_in,
                              void* d_out, int out_size, void* d_ws, size_t ws_size,
                              hipStream_t stream) {
    const float* x = (const float*)d_in[0];
    const float* y = (const float*)d_in[1];
    float* out = (float*)d_out;

    const size_t CY_OFF = 0;         // 8*1024*4 = 32 KB
    const size_t YT_OFF = 32768;     // 8*1024*1024 i8 = 8 MB
    const size_t NEED = YT_OFF + 8388608ull;

    if (ws_size >= NEED) {
        float* cy         = (float*)((char*)d_ws + CY_OFF);
        unsigned char* yt = (unsigned char*)((char*)d_ws + YT_OFF);
        hipMemsetAsync(cy, 0, 32768, stream);
        k_prep_y<<<2048, 256, 0, stream>>>(y, yt, cy);
        k_gemm<<<NG * 64, 256, 0, stream>>>(x, yt, cy, out);
    } else {
        dim3 grid(64, 64, NG), blk(16, 16);
        k_naive<<<grid, blk, 0, stream>>>(x, y, out);
    }
}

// Round 3
// 210.589 us; speedup vs baseline: 1.7415x; 1.7415x over previous
//
#include <hip/hip_runtime.h>
#include <cstdint>

// out[s,b,m,n] = sum_k (x+66)*0.03 * (y-160)*0.025,  S=7 B=8 M=K=N=1024
// y' = y-128; x, y' are exact int8. i8 MFMA (int32-exact):
//   out = 7.5e-4 * ( S' - 32*Rx[m] + 66*Cy[n] - 10813440 ),  S' = sum x*y'
// prep_x: x fp32 -> i8 + row sums Rx.  prep_y: y fp32 -> yt[b][n][k] i8 (y-128) + col sums Cy.
// GEMM: 128x128 tile, 4 waves, BK=64B, dbuf LDS, gload_lds both operands with
// chunk-XOR swizzle (linear LDS dest + inverse-swizzled global src + swizzled read).

#define NG 56

typedef int v4i  __attribute__((ext_vector_type(4)));
typedef int v16i __attribute__((ext_vector_type(16)));

#define GLOAD16(g, l) __builtin_amdgcn_global_load_lds( \
    (const __attribute__((address_space(1))) void*)(g), \
    (__attribute__((address_space(3))) void*)(l), 16, 0, 0)

// fp32 integer-valued [-128,127] -> i8 byte (exponent-pin + bias flip), accumulate sum
__device__ __forceinline__ unsigned pack4(float4 v, float& s) {
    s += (v.x + v.y) + (v.z + v.w);
    unsigned b0 = __float_as_uint(v.x + 8388736.0f);  // 2^23 + 128
    unsigned b1 = __float_as_uint(v.y + 8388736.0f);
    unsigned b2 = __float_as_uint(v.z + 8388736.0f);
    unsigned b3 = __float_as_uint(v.w + 8388736.0f);
    return ((b0 & 0xFFu) | ((b1 & 0xFFu) << 8) | ((b2 & 0xFFu) << 16) | ((b3 & 0xFFu) << 24))
           ^ 0x80808080u;
}

// ---- prepass 1: x -> i8 + row sums. one wave per row ----
__global__ __launch_bounds__(256) void k_prep_x(const float* __restrict__ x,
                                                unsigned char* __restrict__ xb,
                                                float* __restrict__ rx) {
    int row  = blockIdx.x * 4 + (threadIdx.x >> 6);   // 57344 rows
    int lane = threadIdx.x & 63;
    const float* src = x + (size_t)row * 1024;
    float s = 0.f;
#pragma unroll
    for (int it = 0; it < 4; ++it) {
        float4 v = *(const float4*)(src + it * 256 + lane * 4);
        unsigned p = pack4(v, s);
        *(unsigned*)&xb[(size_t)row * 1024 + it * 256 + lane * 4] = p;
    }
#pragma unroll
    for (int off = 32; off > 0; off >>= 1) s += __shfl_down(s, off);
    if (lane == 0) rx[row] = s;
}

// ---- prepass 2: y [b][k][n] -> yt [b][n][k] i8 (= y-128), + col sums Cy ----
__global__ __launch_bounds__(256) void k_prep_y(const float* __restrict__ y,
                                                unsigned char* __restrict__ yt,
                                                float* __restrict__ cy) {
    __shared__ float tile[64][65];
    __shared__ float csum[4][64];
    int b  = blockIdx.x >> 8;
    int t  = blockIdx.x & 255;
    int kt = (t >> 4) * 64, nt = (t & 15) * 64;
    int tx = threadIdx.x & 63;
    int ty = threadIdx.x >> 6;
    const float* src = y + ((size_t)b << 20) + (size_t)kt * 1024 + nt;
    float part = 0.f;
#pragma unroll
    for (int r = 0; r < 16; ++r) {
        int kk = r * 4 + ty;
        float v = src[(size_t)kk * 1024 + tx];
        tile[kk][tx] = v;
        part += v;
    }
    csum[ty][tx] = part;
    __syncthreads();
    if (threadIdx.x < 64) {
        float s = csum[0][tx] + csum[1][tx] + csum[2][tx] + csum[3][tx];
        atomicAdd(&cy[b * 1024 + nt + tx], s);   // exact: integer sums < 2^24
    }
    int ky = threadIdx.x & 15;
    int ny = threadIdx.x >> 4;
#pragma unroll
    for (int r = 0; r < 4; ++r) {
        int nn = r * 16 + ny;
        unsigned b0 = __float_as_uint(tile[ky * 4 + 0][nn] + 8388608.0f);
        unsigned b1 = __float_as_uint(tile[ky * 4 + 1][nn] + 8388608.0f);
        unsigned b2 = __float_as_uint(tile[ky * 4 + 2][nn] + 8388608.0f);
        unsigned b3 = __float_as_uint(tile[ky * 4 + 3][nn] + 8388608.0f);
        unsigned p = ((b0 & 0xFFu) | ((b1 & 0xFFu) << 8) | ((b2 & 0xFFu) << 16) |
                      ((b3 & 0xFFu) << 24)) ^ 0x80808080u;
        *(unsigned*)&yt[((size_t)b << 20) + (size_t)(nt + nn) * 1024 + kt + ky * 4] = p;
    }
}

// ---- GEMM: 128x128, 4 waves, BK=64B, dbuf, i8 MFMA ----
__global__ __launch_bounds__(256) void k_gemm(const unsigned char* __restrict__ xb,
                                              const unsigned char* __restrict__ yt,
                                              const float* __restrict__ rx,
                                              const float* __restrict__ cy,
                                              float* __restrict__ out) {
    __shared__ __align__(16) unsigned char As[2][128 * 64];
    __shared__ __align__(16) unsigned char Bs[2][128 * 64];

    // bijective XCD swizzle (3584 % 8 == 0); consecutive t share A-panel
    int bid = blockIdx.x;
    int wg  = (bid & 7) * (NG * 64 / 8) + (bid >> 3);
    int g   = wg >> 6;
    int t   = wg & 63;
    int m0  = (t >> 3) * 128, n0 = (t & 7) * 128;
    int b   = g & 7;

    int tid = threadIdx.x, lane = tid & 63, w = tid >> 6;
    int wm = w >> 1, wn = w & 1;

    const unsigned char* Ab = xb + (size_t)g * 1048576 + (size_t)m0 * 1024;
    const unsigned char* Bb = yt + ((size_t)b << 20) + (size_t)n0 * 1024;

    // staging: slot c = r*256+tid -> LDS row c>>2, chunk c&3 (16B chunks, 4/row).
    // swizzle: LDS (row, c) holds global (row, c ^ (row&3)).  row&3 == (tid>>2)&3.
    int srow   = tid >> 2;                       // rows 0..63 (r=0), +64 (r=1)
    int schunk = (tid & 3) ^ (srow & 3);
    size_t off0 = (size_t)srow * 1024 + schunk * 16;
    size_t off1 = off0 + 64 * 1024;
    int dst0 = (tid & ~63) * 16;
    int dst1 = (256 + (tid & ~63)) * 16;

#define STAGE(buf, kt) do {                                   \
    GLOAD16(Ab + off0 + (size_t)(kt) * 64, &As[buf][dst0]);   \
    GLOAD16(Ab + off1 + (size_t)(kt) * 64, &As[buf][dst1]);   \
    GLOAD16(Bb + off0 + (size_t)(kt) * 64, &Bs[buf][dst0]);   \
    GLOAD16(Bb + off1 + (size_t)(kt) * 64, &Bs[buf][dst1]);   \
} while (0)

    v16i acc[2][2];
#pragma unroll
    for (int i = 0; i < 2; ++i)
#pragma unroll
        for (int j = 0; j < 2; ++j)
#pragma unroll
            for (int q = 0; q < 16; ++q) acc[i][j][q] = 0;

    // fragment read addresses (swizzled): row = blk*32 + (lane&31),
    // chunk = kk*2 + (lane>>5), swz chunk ^= (row&3) = (lane&3)
    int arow = lane & 31, hi = lane >> 5, rm = lane & 3;
    int rA0 = (wm * 64 + arow) * 64, rA1 = (wm * 64 + 32 + arow) * 64;
    int rB0 = (wn * 64 + arow) * 64, rB1 = (wn * 64 + 32 + arow) * 64;
    int c0 = ((0 + hi) ^ rm) * 16;   // kk=0
    int c1 = ((2 + hi) ^ rm) * 16;   // kk=1

    STAGE(0, 0);
    asm volatile("s_waitcnt vmcnt(0)" ::: "memory");
    __syncthreads();

    int cur = 0;
    for (int kt = 0; kt < 16; ++kt) {
        if (kt < 15) STAGE(cur ^ 1, kt + 1);

        v4i a0k0 = *(const v4i*)&As[cur][rA0 + c0];
        v4i a1k0 = *(const v4i*)&As[cur][rA1 + c0];
        v4i b0k0 = *(const v4i*)&Bs[cur][rB0 + c0];
        v4i b1k0 = *(const v4i*)&Bs[cur][rB1 + c0];
        v4i a0k1 = *(const v4i*)&As[cur][rA0 + c1];
        v4i a1k1 = *(const v4i*)&As[cur][rA1 + c1];
        v4i b0k1 = *(const v4i*)&Bs[cur][rB0 + c1];
        v4i b1k1 = *(const v4i*)&Bs[cur][rB1 + c1];

        acc[0][0] = __builtin_amdgcn_mfma_i32_32x32x32_i8(a0k0, b0k0, acc[0][0], 0, 0, 0);
        acc[0][1] = __builtin_amdgcn_mfma_i32_32x32x32_i8(a0k0, b1k0, acc[0][1], 0, 0, 0);
        acc[1][0] = __builtin_amdgcn_mfma_i32_32x32x32_i8(a1k0, b0k0, acc[1][0], 0, 0, 0);
        acc[1][1] = __builtin_amdgcn_mfma_i32_32x32x32_i8(a1k0, b1k0, acc[1][1], 0, 0, 0);
        acc[0][0] = __builtin_amdgcn_mfma_i32_32x32x32_i8(a0k1, b0k1, acc[0][0], 0, 0, 0);
        acc[0][1] = __builtin_amdgcn_mfma_i32_32x32x32_i8(a0k1, b1k1, acc[0][1], 0, 0, 0);
        acc[1][0] = __builtin_amdgcn_mfma_i32_32x32x32_i8(a1k1, b0k1, acc[1][0], 0, 0, 0);
        acc[1][1] = __builtin_amdgcn_mfma_i32_32x32x32_i8(a1k1, b1k1, acc[1][1], 0, 0, 0);

        if (kt < 15) {
            asm volatile("s_waitcnt vmcnt(0)" ::: "memory");
            __syncthreads();
        }
        cur ^= 1;
    }
#undef STAGE

    // epilogue: out = 7.5e-4 * (S' - 32*Rx + 66*Cy - 10813440)
    // C/D layout (verified): col = lane&31, row = (q&3) + 8*(q>>2) + 4*(lane>>5)
    const float* rxp = rx + g * 1024 + m0 + wm * 64;
    const float* cyp = cy + b * 1024 + n0 + wn * 64;
    float* og = out + (size_t)g * 1048576 + (size_t)(m0 + wm * 64) * 1024 + n0 + wn * 64;
    int col = lane & 31, r4 = hi * 4;
#pragma unroll
    for (int fi = 0; fi < 2; ++fi)
#pragma unroll
        for (int fj = 0; fj < 2; ++fj) {
            int cc = fj * 32 + col;
            float cv = cyp[cc];
            v16i v = acc[fi][fj];
#pragma unroll
            for (int q = 0; q < 16; ++q) {
                int rl = (q & 3) + 8 * (q >> 2) + r4;
                float rxv = rxp[fi * 32 + rl];
                og[(size_t)(fi * 32 + rl) * 1024 + cc] =
                    7.5e-4f * ((float)v[q] - 32.0f * rxv + 66.0f * cv - 10813440.0f);
            }
        }
}

// ---- emergency fallback ----
__global__ void k_naive(const float* __restrict__ x, const float* __restrict__ y,
                        float* __restrict__ out) {
    int g = blockIdx.z, b = g & 7;
    int tx = threadIdx.x, ty = threadIdx.y;
    int m = blockIdx.y * 16 + ty, n = blockIdx.x * 16 + tx;
    __shared__ float a[16][17], bs[16][17];
    float s = 0.f;
    for (int kt = 0; kt < 64; ++kt) {
        a[ty][tx]  = x[(size_t)g * 1048576 + (size_t)m * 1024 + kt * 16 + tx];
        bs[ty][tx] = y[(size_t)b * 1048576 + (size_t)(kt * 16 + ty) * 1024 + n];
        __syncthreads();
#pragma unroll
        for (int j = 0; j < 16; ++j)
            s += ((a[ty][j] + 66.0f) * 0.03f) * ((bs[j][tx] - 160.0f) * 0.025f);
        __syncthreads();
    }
    out[(size_t)g * 1048576 + (size_t)m * 1024 + n] = s;
}

extern "C" void kernel_launch(void* const* d_in, const int* in_sizes, int n_in,
                              void* d_out, int out_size, void* d_ws, size_t ws_size,
                              hipStream_t stream) {
    const float* x = (const float*)d_in[0];
    const float* y = (const float*)d_in[1];
    float* out = (float*)d_out;

    const size_t CY_OFF = 0;                         // 32 KB
    const size_t RX_OFF = 32768;                     // 56*1024*4 = 224 KB
    const size_t YT_OFF = 262144;                    // 8 MB
    const size_t XB_OFF = 262144 + 8388608ull;       // 56 MB
    const size_t NEED   = XB_OFF + 58720256ull;

    if (ws_size >= NEED) {
        float* cy         = (float*)((char*)d_ws + CY_OFF);
        float* rx         = (float*)((char*)d_ws + RX_OFF);
        unsigned char* yt = (unsigned char*)((char*)d_ws + YT_OFF);
        unsigned char* xb = (unsigned char*)((char*)d_ws + XB_OFF);
        hipMemsetAsync(cy, 0, 32768, stream);
        k_prep_x<<<14336, 256, 0, stream>>>(x, xb, rx);
        k_prep_y<<<2048, 256, 0, stream>>>(y, yt, cy);
        k_gemm<<<NG * 64, 256, 0, stream>>>(xb, yt, rx, cy, out);
    } else {
        dim3 grid(64, 64, NG), blk(16, 16);
        k_naive<<<grid, blk, 0, stream>>>(x, y, out);
    }
}